// Round 10
// baseline (185.785 us; speedup 1.0000x reference)
//
#include <hip/hip_runtime.h>
#include <hip/hip_bf16.h>

// ---------------------------------------------------------------------------
// HessianCompatibleMultiHeadAttention on MI355X (gfx950).
// Inputs fp32, output fp32. Internal bf16 MFMA.
// B=2, S=2048, D=1024, H=16, Dk=64.
//   cvt_all:   x, wq, wk, wv, wo -> bf16
//   gemm_qkv:  Q,K,V = x_bf @ {Wq,Wk,Wv}^T in ONE kernel — BM=128 BN=64
//              BK=64, all 3 z fused per block: A-panel staged ONCE for 3
//              planes (r9 lesson: per-z BN=64 halved density; fusion restores
//              48 MFMA per 4 A-frag reads). Q pre-scaled 0.125*log2e; V
//              epilogue writes V^T directly (r8/r9-verified transpose).
//   attn4:     flash attention q-tile 64, kv-split, in-register P
//              (cvt_pk + permlane32_swap). [49.5-51.3 us — FROZEN: dbuf(r8),
//              setprio(r6), reg-prefetch(r5) all null/neg]
//   gemm_out:  out = ab @ Wo^T + b_o, BM=128 BN=128 (r7-verified shape).
// Workspace planes (8 MB each): 0=Q 1=K 2=V^T 3=x_bf/ab 4..=weights bf16.
// ---------------------------------------------------------------------------

typedef __bf16 bf16x8 __attribute__((ext_vector_type(8)));
typedef float f32x4 __attribute__((ext_vector_type(4)));
typedef float f32x16 __attribute__((ext_vector_type(16)));

__device__ __forceinline__ unsigned short f2bf(float f) {
  union { float f; unsigned int u; } c; c.f = f;
  unsigned int u = c.u;
  return (unsigned short)((u + 0x7FFFu + ((u >> 16) & 1u)) >> 16);
}

// pack two fp32 -> [bf16(a) | bf16(b)<<16] in ONE VALU op (T12 recipe)
__device__ __forceinline__ unsigned int cvtpk(float a, float b) {
  unsigned int r;
  asm("v_cvt_pk_bf16_f32 %0, %1, %2" : "=v"(r) : "v"(a), "v"(b));
  return r;
}

__device__ __forceinline__ bf16x8 ld_frag(const unsigned short* p) {
  union { uint4 u; bf16x8 b; } c;
  c.u = *(const uint4*)p;   // 16B aligned -> ds_read_b128
  return c.b;
}

__device__ __forceinline__ uint4 cvt8(const float* __restrict__ p) {
  float4 a = *(const float4*)p;
  float4 b = *(const float4*)(p + 4);
  union { uint4 u; unsigned short s[8]; } r;
  r.s[0] = f2bf(a.x); r.s[1] = f2bf(a.y); r.s[2] = f2bf(a.z); r.s[3] = f2bf(a.w);
  r.s[4] = f2bf(b.x); r.s[5] = f2bf(b.y); r.s[6] = f2bf(b.z); r.s[7] = f2bf(b.w);
  return r.u;
}

// async global->LDS, 16B per lane (lds dest = wave-uniform base + lane*16)
typedef __attribute__((address_space(1))) const unsigned int as1_u32;
typedef __attribute__((address_space(3))) unsigned int as3_u32;
__device__ __forceinline__ void async16(const unsigned short* g,
                                        unsigned short* l) {
  __builtin_amdgcn_global_load_lds(
      (as1_u32*)(unsigned long long)g,
      (as3_u32*)(unsigned int)(unsigned long long)l, 16, 0, 0);
}

// ---------------------------------------------------------------------------
// fp32 -> bf16 conversion (memory-bound). grid (2048, 5).
// ---------------------------------------------------------------------------
__global__ __launch_bounds__(256) void cvt_all(
    const float* __restrict__ s0, const float* __restrict__ s1,
    const float* __restrict__ s2, const float* __restrict__ s3,
    const float* __restrict__ s4,
    unsigned short* __restrict__ d0, unsigned short* __restrict__ d1,
    unsigned short* __restrict__ d2, unsigned short* __restrict__ d3,
    unsigned short* __restrict__ d4) {
  const float* srcs[5] = {s0, s1, s2, s3, s4};
  unsigned short* dsts[5] = {d0, d1, d2, d3, d4};
  const int ns[5] = {4194304, 1048576, 1048576, 1048576, 1048576};
  const int y = blockIdx.y;
  const int idx = (blockIdx.x * 256 + threadIdx.x) * 8;
  if (idx >= ns[y]) return;
  *(uint4*)(dsts[y] + idx) = cvt8(srcs[y] + idx);
}

// ---------------------------------------------------------------------------
// gemm_qkv: {Q,K,V}[m][n] = sum_k x[m][k] W{q,k,v}[n][k], z-FUSED.
// BM=128, BN=64, BK=64, 256 thr, 4 waves as 2x2 of 64m x 32n.
// Per k-step: stage A once (128 rows) + 3 B panels (3 x 64 rows); each wave's
// 4 A-frag reads feed 48 MFMAs (3z x 2kk x 4mt x 2nt / 2kk... = 16 per kk
// per z-pair) -- A staging traffic HALVED vs separate-z, density 3x.
// Grid (32 m, 16 n) = 512 blocks (2/CU); ids sharing an m-tile differ by 32
// (=0 mod 8) -> same XCD -> A-panel L2-local.
// LDS 40 KB; acc[3][4][2] f32x4 = 96 VGPR (static indices only).
// Staging: global_load_lds w=16, 8-row 1 KiB chunks, slot^(row&7) XOR
// swizzle pre-applied to the GLOBAL source address (LDS dest linear).
// Epilogues: z=0 Q*qscale -> plane 0; z=1 K -> plane 1; z=2 V -> V^T
// [bh][d][s] via in-LDS transpose (r8/r9-verified BN=64 path) -> plane 2.
// ---------------------------------------------------------------------------
__global__ __launch_bounds__(256, 2) void gemm_qkv(
    const unsigned short* __restrict__ A,
    const unsigned short* __restrict__ w0,
    const unsigned short* __restrict__ w1,
    const unsigned short* __restrict__ w2,
    unsigned short* __restrict__ out, float qscale) {
  constexpr size_t PL = (size_t)4096 * 1024;
  __shared__ unsigned short smem[(128 + 3 * 64) * 64];  // 40 KB
  unsigned short* a_lds = smem;
  unsigned short* b_lds = smem + 128 * 64;  // [z][64][64]

  const int tid = threadIdx.x;
  const int wave = tid >> 6, lane = tid & 63;
  const int quad = lane >> 4, l16 = lane & 15;
  const int wm = (wave >> 1) * 64, wn = (wave & 1) * 32;
  const int bm = blockIdx.x * 128, bn = blockIdx.y * 64;

  const int r8 = lane >> 3;            // row within 8-row chunk
  const int sl = (lane & 7) ^ r8;      // inverse-swizzled k-chunk (16B units)
  const unsigned short* ga = A + (size_t)(bm + wave * 32 + r8) * 1024 + sl * 8;
  const unsigned short* gw0 = w0 + (size_t)(bn + wave * 16 + r8) * 1024 + sl * 8;
  const unsigned short* gw1 = w1 + (size_t)(bn + wave * 16 + r8) * 1024 + sl * 8;
  const unsigned short* gw2 = w2 + (size_t)(bn + wave * 16 + r8) * 1024 + sl * 8;
  unsigned short* la = &a_lds[wave * 32 * 64];
  unsigned short* lb0 = &b_lds[0 * 4096 + wave * 16 * 64];
  unsigned short* lb1 = &b_lds[1 * 4096 + wave * 16 * 64];
  unsigned short* lb2 = &b_lds[2 * 4096 + wave * 16 * 64];

  f32x4 acc[3][4][2] = {};

  for (int k0 = 0; k0 < 1024; k0 += 64) {
    // ---- stage A (32 rows/wave) and 3x B (16 rows/wave each) ----
#pragma unroll
    for (int c = 0; c < 4; ++c)
      async16(ga + (size_t)c * 8 * 1024, la + c * 512);
#pragma unroll
    for (int c = 0; c < 2; ++c) {
      async16(gw0 + (size_t)c * 8 * 1024, lb0 + c * 512);
      async16(gw1 + (size_t)c * 8 * 1024, lb1 + c * 512);
      async16(gw2 + (size_t)c * 8 * 1024, lb2 + c * 512);
    }
    ga += 64; gw0 += 64; gw1 += 64; gw2 += 64;
    __syncthreads();

#pragma unroll
    for (int kk = 0; kk < 2; ++kk) {
      bf16x8 af[4];
#pragma unroll
      for (int t = 0; t < 4; ++t) {
        const int row = wm + t * 16 + l16;
        af[t] =
            ld_frag(&a_lds[row * 64 + (((kk * 4 + quad) ^ (row & 7)) * 8)]);
      }
#pragma unroll
      for (int z = 0; z < 3; ++z) {
        bf16x8 bfr[2];
#pragma unroll
        for (int t = 0; t < 2; ++t) {
          const int row = wn + t * 16 + l16;
          bfr[t] = ld_frag(&b_lds[z * 4096 + row * 64 +
                                  (((kk * 4 + quad) ^ (row & 7)) * 8)]);
        }
#pragma unroll
        for (int mt = 0; mt < 4; ++mt)
#pragma unroll
          for (int nt = 0; nt < 2; ++nt)
            acc[z][mt][nt] = __builtin_amdgcn_mfma_f32_16x16x32_bf16(
                af[mt], bfr[nt], acc[z][mt][nt], 0, 0, 0);
      }
    }
    __syncthreads();
  }

  // ---- epilogue z=0 (Q, scaled) and z=1 (K): direct bf16 stores ----
  // C/D layout: col = lane&15, row = quad*4 + reg  [m89-verified]
#pragma unroll
  for (int z = 0; z < 2; ++z) {
    const float scl = (z == 0) ? qscale : 1.0f;
#pragma unroll
    for (int nt = 0; nt < 2; ++nt) {
      const int n = bn + wn + nt * 16 + l16;
#pragma unroll
      for (int mt = 0; mt < 4; ++mt)
#pragma unroll
        for (int r = 0; r < 4; ++r) {
          const int m = bm + wm + mt * 16 + quad * 4 + r;
          out[(size_t)z * PL + (size_t)m * 1024 + n] =
              f2bf(acc[z][mt][nt][r] * scl);
        }
    }
  }

  // ---- epilogue z=2 (V): transposed -> V^T [bh][d][s] into plane 2 ----
  {
    unsigned short* tt = smem;  // [64 d][128 s] bf16, 8-short-granule swizzle
#pragma unroll
    for (int nt = 0; nt < 2; ++nt) {
      const int d = wn + nt * 16 + l16;
#pragma unroll
      for (int mt = 0; mt < 4; ++mt) {
        const int ml = wm + mt * 16 + quad * 4;
        union { uint2 u; unsigned short s[4]; } pk;
#pragma unroll
        for (int r = 0; r < 4; ++r) pk.s[r] = f2bf(acc[2][mt][nt][r]);
        const int g = (ml >> 3) ^ (d & 7);
        *(uint2*)&tt[d * 128 + g * 8 + (ml & 7)] = pk.u;
      }
    }
    __syncthreads();
    const int d = tid >> 2, qtr = tid & 3;
    const int bb = bm >> 11, s0 = bm & 2047, hh = bn >> 6;
    unsigned short* vtp = out + (size_t)2 * PL +
                          ((size_t)(bb * 16 + hh)) * 131072 +
                          (size_t)d * 2048 + s0 + qtr * 32;
#pragma unroll
    for (int k = 0; k < 4; ++k) {
      const int g = (qtr * 4 + k) ^ (d & 7);
      *(uint4*)&vtp[k * 8] = *(const uint4*)&tt[d * 128 + g * 8];
    }
  }
}

// ---------------------------------------------------------------------------
// gemm_out: out[m][n] = sum_k ab[m][k] Wo[n][k] + b_o[n], fp32 out.
// BM=128, BN=128, BK=64 (r7-verified shape), 4 waves 2x2 of 64x64.
// Grid (32 m, 8 n) = 256 blocks; m fast dim -> A-panel XCD-local.
// ---------------------------------------------------------------------------
__global__ __launch_bounds__(256, 3) void gemm_out(
    const unsigned short* __restrict__ A,
    const unsigned short* __restrict__ W,
    const float* __restrict__ bias, float* __restrict__ out) {
  __shared__ unsigned short smem[256 * 64];  // 32 KB: A 128 rows + B 128 rows
  unsigned short* a_lds = smem;
  unsigned short* b_lds = smem + 128 * 64;

  const int tid = threadIdx.x;
  const int wave = tid >> 6, lane = tid & 63;
  const int quad = lane >> 4, l16 = lane & 15;
  const int wm = (wave >> 1) * 64, wn = (wave & 1) * 64;
  const int bm = blockIdx.x * 128, bn = blockIdx.y * 128;

  const int r8 = lane >> 3;
  const int sl = (lane & 7) ^ r8;
  const unsigned short* ga = A + (size_t)(bm + wave * 32 + r8) * 1024 + sl * 8;
  const unsigned short* gb = W + (size_t)(bn + wave * 32 + r8) * 1024 + sl * 8;
  unsigned short* la = &a_lds[wave * 32 * 64];
  unsigned short* lb = &b_lds[wave * 32 * 64];

  f32x4 acc[4][4] = {};

  for (int k0 = 0; k0 < 1024; k0 += 64) {
#pragma unroll
    for (int c = 0; c < 4; ++c) {
      async16(ga + (size_t)c * 8 * 1024, la + c * 512);
      async16(gb + (size_t)c * 8 * 1024, lb + c * 512);
    }
    ga += 64; gb += 64;
    __syncthreads();

    bf16x8 af[2][4], bfr[2][4];
#pragma unroll
    for (int kk = 0; kk < 2; ++kk) {
#pragma unroll
      for (int t = 0; t < 4; ++t) {
        const int ra = wm + t * 16 + l16;
        af[kk][t] =
            ld_frag(&a_lds[ra * 64 + (((kk * 4 + quad) ^ (ra & 7)) * 8)]);
        const int rb = wn + t * 16 + l16;
        bfr[kk][t] =
            ld_frag(&b_lds[rb * 64 + (((kk * 4 + quad) ^ (rb & 7)) * 8)]);
      }
    }
#pragma unroll
    for (int kk = 0; kk < 2; ++kk)
#pragma unroll
      for (int mt = 0; mt < 4; ++mt)
#pragma unroll
        for (int nt = 0; nt < 4; ++nt)
          acc[mt][nt] = __builtin_amdgcn_mfma_f32_16x16x32_bf16(
              af[kk][mt], bfr[kk][nt], acc[mt][nt], 0, 0, 0);
    __syncthreads();
  }

  // Epilogue: C/D layout col = lane&15, row = quad*4 + reg  [m89-verified]
#pragma unroll
  for (int nt = 0; nt < 4; ++nt) {
    const int n = bn + wn + nt * 16 + l16;
    const float bv = bias[n];
#pragma unroll
    for (int mt = 0; mt < 4; ++mt)
#pragma unroll
      for (int r = 0; r < 4; ++r) {
        const int m = bm + wm + mt * 16 + quad * 4 + r;
        out[(size_t)m * 1024 + n] = acc[mt][nt][r] + bv;
      }
  }
}

// ---------------------------------------------------------------------------
// Flash attention, q-tile 64, in-block kv-split, no-max exp2 softmax
// (Q pre-scaled by 0.125*log2e).  [r7/r9-verified ~50 us — FROZEN]
//
// Block: 256 thr = 4 waves = 2 q-groups (wq) x 2 kv-streams (ws).
//   wave (wq,ws): 32 q rows = qt*64 + wq*32, kv range = ws*1024 .. +1023,
//   iterated in 16 tiles of KVBLK=64.
// MFMA 32x32x16, S^T form (A = K rows, B = Q cols): lane (hi,l32) holds
//   S^T col q=l32, rows kv = 32mb + 4hi + (r&3) + 8(r>>2)  [m74/m101 layout].
// P stays IN REGISTERS: cvt_pk pairs -> u[mb][g][p] (kv = 32mb+4hi+8g+2p+{0,1});
//   2x v_permlane32_swap_b32 per k-chunk assembles the PV A-frag
//   (lane needs P[q][16ks+8hi+j]) -- no P LDS round-trip, no P barrier.
// LDS: per stream K tile [64 kv][64 d] + V^T tile [64 d][64 kv], 64-short rows
//   with slot^(row&7) XOR swizzle; staged by global_load_lds w=16 with the
//   inverse swizzle pre-applied to the per-lane GLOBAL source address
//   (LDS dest stays linear). Conflict-free ds_read_b128 frag reads.
// Epilogue: streams combine unnormalized O (fp32) + l through LDS (exp2
//   softmax has no running max -> partials are additive), normalize, store.
// LDS 33280 B, VGPR <=128 (launch_bounds 256,4) -> 4 blocks/CU = 16 waves/CU.
// grid (32 qt, 32 bh) = 1024 blocks.
// ---------------------------------------------------------------------------
__global__ __launch_bounds__(256, 4) void attn4(
    const unsigned short* __restrict__ qkv,   // Q plane at 0, K plane at PL
    const unsigned short* __restrict__ vt_g,  // [32][64][2048] (plane 2)
    unsigned short* __restrict__ ab) {
  constexpr size_t PL = (size_t)4096 * 1024;
  const int qt = blockIdx.x, bh = blockIdx.y;
  const int b = bh >> 4, h = bh & 15;

  __shared__ __align__(16) unsigned short kvs[2][2][64 * 64];  // [ws][K,V][.]
  __shared__ float sm_l[2][2][32];                             // [ws][wq][q]

  const int tid = threadIdx.x;
  const int wave = tid >> 6, lane = tid & 63;
  const int ws = wave >> 1, wq = wave & 1;
  const int hi = lane >> 5, l32 = lane & 31;
  const int row8 = lane >> 3;                  // 0..7 (staging row in chunk)
  const int sl = (lane & 7) ^ (row8 & 7);      // pre-swizzled source slot
  const int swz = (l32 & 7) * 8;               // read-side XOR (shorts)

  // Q fragments (B operand): lane holds Q[q=l32][d = kc*16 + hi*8 + j]
  const unsigned short* qrow =
      qkv + (size_t)(b * 2048 + qt * 64 + wq * 32 + l32) * 1024 + h * 64 +
      hi * 8;
  bf16x8 qf[4];
#pragma unroll
  for (int kc = 0; kc < 4; ++kc) qf[kc] = ld_frag(qrow + kc * 16);

  // staging pointers: per-lane global (swizzled), wave-uniform LDS base.
  // wave wq stages chunks wq*4..wq*4+3 (1 KiB each) of its stream's K and V.
  const unsigned short* gK =
      qkv + PL + (size_t)(b * 2048 + ws * 1024 + wq * 32 + row8) * 1024 +
      h * 64 + sl * 8;
  const unsigned short* gV =
      vt_g + (size_t)bh * 64 * 2048 + (size_t)(wq * 32 + row8) * 2048 +
      ws * 1024 + sl * 8;
  unsigned short* lK = &kvs[ws][0][wq * 4 * 512];
  unsigned short* lV = &kvs[ws][1][wq * 4 * 512];

  f32x16 o_acc[2] = {};
  float l_part = 0.0f;

  for (int t = 0; t < 16; ++t) {
    // ---- stage K,V tiles (64 kv) for this stream ----
#pragma unroll
    for (int c = 0; c < 4; ++c) {
      async16(gK + (size_t)c * 8 * 1024, lK + c * 512);
      async16(gV + (size_t)c * 8 * 2048, lV + c * 512);
    }
    gK += 64 * 1024;  // next 64 kv rows
    gV += 64;         // next 64 kv cols
    __syncthreads();

    // ---- QK^T: S^T[kv][q], 2 mb x 4 kc ----
    f32x16 st[2] = {};
#pragma unroll
    for (int mb = 0; mb < 2; ++mb)
#pragma unroll
      for (int kc = 0; kc < 4; ++kc) {
        bf16x8 ak = ld_frag(
            &kvs[ws][0][(mb * 32 + l32) * 64 + (((2 * kc + hi) * 8) ^ swz)]);
        st[mb] = __builtin_amdgcn_mfma_f32_32x32x16_bf16(ak, qf[kc], st[mb],
                                                         0, 0, 0);
      }

    // ---- softmax (no-max exp2) + pack P to bf16 pairs in registers ----
    unsigned int u[2][4][2];
#pragma unroll
    for (int mb = 0; mb < 2; ++mb) {
#pragma unroll
      for (int r = 0; r < 16; ++r) {
        const float p = __builtin_amdgcn_exp2f(st[mb][r]);
        st[mb][r] = p;
        l_part += p;
      }
#pragma unroll
      for (int g = 0; g < 4; ++g) {
        u[mb][g][0] = cvtpk(st[mb][g * 4 + 0], st[mb][g * 4 + 1]);
        u[mb][g][1] = cvtpk(st[mb][g * 4 + 2], st[mb][g * 4 + 3]);
      }
    }

    // ---- PV: O += P.V, A-frags assembled via permlane32_swap ----
#pragma unroll
    for (int ks = 0; ks < 4; ++ks) {
      const int m = ks >> 1, g = (ks & 1) * 2;
      unsigned int a0 = u[m][g][0], b0 = u[m][g + 1][0];
      unsigned int a1 = u[m][g][1], b1 = u[m][g + 1][1];
      // after swap: a' = [a.lo | b.lo], b' = [a.hi | b.hi]
      asm("v_permlane32_swap_b32 %0, %1" : "+v"(a0), "+v"(b0));
      asm("v_permlane32_swap_b32 %0, %1" : "+v"(a1), "+v"(b1));
      union { unsigned int w[4]; bf16x8 f; } pa;
      pa.w[0] = a0; pa.w[1] = a1; pa.w[2] = b0; pa.w[3] = b1;
#pragma unroll
      for (int nb = 0; nb < 2; ++nb) {
        bf16x8 bv = ld_frag(
            &kvs[ws][1][(nb * 32 + l32) * 64 + (((2 * ks + hi) * 8) ^ swz)]);
        o_acc[nb] = __builtin_amdgcn_mfma_f32_32x32x16_bf16(pa.f, bv,
                                                            o_acc[nb], 0, 0, 0);
      }
    }
    __syncthreads();  // all frag reads done -> restage safe
  }

  // ---- cross-stream combine: O = (O0+O1) / (l0+l1) ----
  float lsum = l_part + __shfl_xor(l_part, 32);  // full kv-half sum, q=l32

  float* sm_o = (float*)&kvs[0][0][0];  // [2 wq][32 q][64 d] fp32 = 16 KiB
  if (ws == 1) {
#pragma unroll
    for (int nb = 0; nb < 2; ++nb)
#pragma unroll
      for (int r = 0; r < 16; ++r) {
        const int q = (r & 3) + 8 * (r >> 2) + 4 * hi;
        sm_o[wq * 2048 + q * 64 + nb * 32 + l32] = o_acc[nb][r];
      }
  }
  if (lane < 32) sm_l[ws][wq][l32] = lsum;
  __syncthreads();

  if (ws == 0) {
#pragma unroll
    for (int r = 0; r < 16; ++r) {
      const int q = (r & 3) + 8 * (r >> 2) + 4 * hi;
      const float inv = 1.0f / (sm_l[0][wq][q] + sm_l[1][wq][q]);
      const size_t row = (size_t)(b * 2048 + qt * 64 + wq * 32 + q);
#pragma unroll
      for (int nb = 0; nb < 2; ++nb) {
        const float v =
            (o_acc[nb][r] + sm_o[wq * 2048 + q * 64 + nb * 32 + l32]) * inv;
        ab[row * 1024 + h * 64 + nb * 32 + l32] = f2bf(v);
      }
    }
  }
}

// ---------------------------------------------------------------------------
extern "C" void kernel_launch(void* const* d_in, const int* in_sizes, int n_in,
                              void* d_out, int out_size, void* d_ws,
                              size_t ws_size, hipStream_t stream) {
  const float* x  = (const float*)d_in[0];
  const float* wq = (const float*)d_in[1];
  const float* wk = (const float*)d_in[2];
  const float* wv = (const float*)d_in[3];
  const float* wo = (const float*)d_in[4];
  const float* bo = (const float*)d_in[5];

  constexpr size_t PL = (size_t)4096 * 1024;
  unsigned short* qkv = (unsigned short*)d_ws;   // planes 0=Q 1=K 2=V^T
  unsigned short* xb  = qkv + 3 * PL;            // x bf16 (dead after gemm)
  unsigned short* ab  = xb;                      // attn out overlays xb
  unsigned short* wqb = qkv + 4 * PL;
  unsigned short* wkb = wqb + 1024 * 1024;
  unsigned short* wvb = wkb + 1024 * 1024;
  unsigned short* wob = wvb + 1024 * 1024;

  const float QSCALE = 0.18033688011112042f;  // 0.125 * log2(e)

  cvt_all<<<dim3(2048, 5), 256, 0, stream>>>(x, wq, wk, wv, wo,
                                             xb, wqb, wkb, wvb, wob);
  gemm_qkv<<<dim3(32, 16), 256, 0, stream>>>(xb, wqb, wkb, wvb, qkv, QSCALE);
  attn4<<<dim3(32, 32), 256, 0, stream>>>(qkv, qkv + 2 * PL, ab);
  gemm_out<<<dim3(32, 8), 256, 0, stream>>>(ab, wob, bo, (float*)d_out);
}

// Round 11
// 183.167 us; speedup vs baseline: 1.0143x; 1.0143x over previous
//
#include <hip/hip_runtime.h>
#include <hip/hip_bf16.h>

// ---------------------------------------------------------------------------
// HessianCompatibleMultiHeadAttention on MI355X (gfx950).
// Inputs fp32, output fp32. Internal bf16 MFMA.
// B=2, S=2048, D=1024, H=16, Dk=64.
//   cvt_all:      x, wq, wk, wv, wo  -> bf16
//   gemm_bt<false>: qkv = x_bf @ W^T (z=0 Q pre-scaled 0.125*log2e),
//                 BM=128 BN=128 BK=64, grid (32,8,3) [r7-verified config],
//                 MFMA 32x32x16 (r10: 16 inst/k-step @8cy vs 32 @4.85cy),
//                 z==2 (V) epilogue writes V^T directly (in-LDS transpose).
//   attn4:        flash attention q-tile 64, kv-split, in-register P
//                 (cvt_pk + permlane32_swap). [~50 us — FROZEN: dbuf(r8),
//                 setprio(r6), reg-prefetch(r5) all null/neg]
//   gemm_bt<true>: out = ab @ Wo^T + b_o (fp32), grid (32,8,1).
// Workspace planes (8 MB each): 0=Q 1=K 2=V^T 3=x_bf/ab 4..=weights bf16.
// r9/r10 lesson: BN=64 geometry (per-z or z-fused) loses ~7 us vs r7's
// BN=128 — per-wave density + occupancy beat A-staging dedup.
// ---------------------------------------------------------------------------

typedef __bf16 bf16x8 __attribute__((ext_vector_type(8)));
typedef float f32x4 __attribute__((ext_vector_type(4)));
typedef float f32x16 __attribute__((ext_vector_type(16)));

__device__ __forceinline__ unsigned short f2bf(float f) {
  union { float f; unsigned int u; } c; c.f = f;
  unsigned int u = c.u;
  return (unsigned short)((u + 0x7FFFu + ((u >> 16) & 1u)) >> 16);
}

// pack two fp32 -> [bf16(a) | bf16(b)<<16] in ONE VALU op (T12 recipe)
__device__ __forceinline__ unsigned int cvtpk(float a, float b) {
  unsigned int r;
  asm("v_cvt_pk_bf16_f32 %0, %1, %2" : "=v"(r) : "v"(a), "v"(b));
  return r;
}

__device__ __forceinline__ bf16x8 ld_frag(const unsigned short* p) {
  union { uint4 u; bf16x8 b; } c;
  c.u = *(const uint4*)p;   // 16B aligned -> ds_read_b128
  return c.b;
}

__device__ __forceinline__ uint4 cvt8(const float* __restrict__ p) {
  float4 a = *(const float4*)p;
  float4 b = *(const float4*)(p + 4);
  union { uint4 u; unsigned short s[8]; } r;
  r.s[0] = f2bf(a.x); r.s[1] = f2bf(a.y); r.s[2] = f2bf(a.z); r.s[3] = f2bf(a.w);
  r.s[4] = f2bf(b.x); r.s[5] = f2bf(b.y); r.s[6] = f2bf(b.z); r.s[7] = f2bf(b.w);
  return r.u;
}

// async global->LDS, 16B per lane (lds dest = wave-uniform base + lane*16)
typedef __attribute__((address_space(1))) const unsigned int as1_u32;
typedef __attribute__((address_space(3))) unsigned int as3_u32;
__device__ __forceinline__ void async16(const unsigned short* g,
                                        unsigned short* l) {
  __builtin_amdgcn_global_load_lds(
      (as1_u32*)(unsigned long long)g,
      (as3_u32*)(unsigned int)(unsigned long long)l, 16, 0, 0);
}

// ---------------------------------------------------------------------------
// fp32 -> bf16 conversion (memory-bound). grid (2048, 5).
// ---------------------------------------------------------------------------
__global__ __launch_bounds__(256) void cvt_all(
    const float* __restrict__ s0, const float* __restrict__ s1,
    const float* __restrict__ s2, const float* __restrict__ s3,
    const float* __restrict__ s4,
    unsigned short* __restrict__ d0, unsigned short* __restrict__ d1,
    unsigned short* __restrict__ d2, unsigned short* __restrict__ d3,
    unsigned short* __restrict__ d4) {
  const float* srcs[5] = {s0, s1, s2, s3, s4};
  unsigned short* dsts[5] = {d0, d1, d2, d3, d4};
  const int ns[5] = {4194304, 1048576, 1048576, 1048576, 1048576};
  const int y = blockIdx.y;
  const int idx = (blockIdx.x * 256 + threadIdx.x) * 8;
  if (idx >= ns[y]) return;
  *(uint4*)(dsts[y] + idx) = cvt8(srcs[y] + idx);
}

// ---------------------------------------------------------------------------
// GEMM: C[m][n] = scl * sum_k A[m][k] W[n][k] (+ bias[n]); bf16 in, fp32 acc.
// BM=128, BN=128, BK=64, 256 thr, 4 waves 2x2 of 64x64; MFMA 32x32x16:
// per wave-k-step 16 MFMA (8cy) + 16 ds_read_b128 — same reads, 17% less
// matrix-pipe time and half the issue slots vs the 16x16x32 form (m119).
// qkv path grid (32,8,3); out path grid (32,8,1). x = m-tile (fast dim) ->
// the 8 n-blocks sharing an A-panel land on ONE XCD -> A-panel L2-local.
// Staging: global_load_lds w=16, 8-row 1 KiB chunks; LDS [row][64] with
// slot^(row&7) XOR swizzle pre-applied to the per-lane GLOBAL source
// address (LDS dest linear). Frag reads: row = tile + l32, chunk =
// (2*ks+hi) ^ (row&7) — attn4's verified K-read geometry.
// C/D layout (32x32): col = l32, row = (r&3)+8*(r>>2)+4*hi [m74/m101].
// z==2 (V plane, !OUT_F32): epilogue transposes the 128x128 C-tile in LDS
// (8-short granule XOR swizzle) and writes V^T [bh][d][s] into plane 2
// (store-out phase byte-identical to the r5-r7-verified version).
// ---------------------------------------------------------------------------
template <bool OUT_F32>
__global__ __launch_bounds__(256, 3) void gemm_bt(
    const unsigned short* __restrict__ A,
    const unsigned short* __restrict__ w0,
    const unsigned short* __restrict__ w1,
    const unsigned short* __restrict__ w2,
    const float* __restrict__ bias,
    void* __restrict__ outraw, float z0scale) {
  const int z = blockIdx.z;
  const unsigned short* W = (z == 0) ? w0 : ((z == 1) ? w1 : w2);
  const float scl = (z == 0) ? z0scale : 1.0f;

  __shared__ unsigned short smem[256 * 64];  // 32 KB: A 128 rows + B 128 rows
  unsigned short* a_lds = smem;
  unsigned short* b_lds = smem + 128 * 64;

  const int tid = threadIdx.x;
  const int wave = tid >> 6, lane = tid & 63;
  const int hi = lane >> 5, l32 = lane & 31;
  const int wm = (wave >> 1) * 64, wn = (wave & 1) * 64;
  const int bm = blockIdx.x * 128, bn = blockIdx.y * 128;

  // staging: 1 KiB chunk = 8 rows x 64 shorts; lane covers (row8, slot)
  const int r8 = lane >> 3;            // row within chunk (0..7)
  const int sl = (lane & 7) ^ r8;      // inverse-swizzled k-chunk (16B units)
  const unsigned short* ga = A + (size_t)(bm + wave * 32 + r8) * 1024 + sl * 8;
  const unsigned short* gb = W + (size_t)(bn + wave * 32 + r8) * 1024 + sl * 8;
  unsigned short* la = &a_lds[wave * 32 * 64];
  unsigned short* lb = &b_lds[wave * 32 * 64];

  f32x16 acc[2][2] = {};

  for (int k0 = 0; k0 < 1024; k0 += 64) {
    // ---- stage A (32 rows/wave) and B (32 rows/wave) ----
#pragma unroll
    for (int c = 0; c < 4; ++c) {
      async16(ga + (size_t)c * 8 * 1024, la + c * 512);
      async16(gb + (size_t)c * 8 * 1024, lb + c * 512);
    }
    ga += 64; gb += 64;
    __syncthreads();

    // ---- frag reads: A rows = wm+mt*32+l32, B rows = wn+nt*32+l32 ----
    bf16x8 af[2][4], bfr[2][4];   // [tile][k-slice]
#pragma unroll
    for (int mt = 0; mt < 2; ++mt) {
      const int ra = wm + mt * 32 + l32;
      const int rb = wn + mt * 32 + l32;
#pragma unroll
      for (int ks = 0; ks < 4; ++ks) {
        af[mt][ks] =
            ld_frag(&a_lds[ra * 64 + (((2 * ks + hi) ^ (ra & 7)) * 8)]);
        bfr[mt][ks] =
            ld_frag(&b_lds[rb * 64 + (((2 * ks + hi) ^ (rb & 7)) * 8)]);
      }
    }
#pragma unroll
    for (int ks = 0; ks < 4; ++ks)
#pragma unroll
      for (int mt = 0; mt < 2; ++mt)
#pragma unroll
        for (int nt = 0; nt < 2; ++nt)
          acc[mt][nt] = __builtin_amdgcn_mfma_f32_32x32x16_bf16(
              af[mt][ks], bfr[nt][ks], acc[mt][nt], 0, 0, 0);
    __syncthreads();
  }

  // ---- z==2 (V): transposed epilogue -> V^T [bh][d][s] into plane 2 ----
  if (!OUT_F32 && z == 2) {
    unsigned short* tt = smem;  // [128 n][128 m] bf16, 8-short-granule swizzle
#pragma unroll
    for (int nt = 0; nt < 2; ++nt)
#pragma unroll
      for (int mt = 0; mt < 2; ++mt)
#pragma unroll
        for (int g = 0; g < 4; ++g) {
          const int d = wn + nt * 32 + l32;               // n index in block
          const int ml = wm + mt * 32 + g * 8 + hi * 4;   // m base (4 rows)
          union { uint2 u; unsigned short s[4]; } pk;
#pragma unroll
          for (int j = 0; j < 4; ++j)
            pk.s[j] = f2bf(acc[mt][nt][g * 4 + j]);
          const int gr = (ml >> 3) ^ (d & 7);
          *(uint2*)&tt[d * 128 + gr * 8 + (ml & 7)] = pk.u;
        }
    __syncthreads();
    const int nl = tid >> 1, sc = (tid & 1) * 64;
    const int bb = bm >> 11, s0 = bm & 2047;
    const int hh = (bn >> 6) + (nl >> 6);
    unsigned short* vtp = (unsigned short*)outraw + (size_t)2 * 4096 * 1024 +
                          ((size_t)(bb * 16 + hh)) * 131072 +
                          (size_t)(nl & 63) * 2048 + s0 + sc;
#pragma unroll
    for (int k = 0; k < 8; ++k) {
      const int g = ((sc + k * 8) >> 3) ^ (nl & 7);
      *(uint4*)&vtp[k * 8] = *(const uint4*)&tt[nl * 128 + g * 8];
    }
    return;
  }

  // ---- epilogue: col = l32, row = (r&3)+8*(r>>2)+4*hi [m74/m101] ----
#pragma unroll
  for (int nt = 0; nt < 2; ++nt) {
    const int n = bn + wn + nt * 32 + l32;
    const float bv = bias ? bias[n] : 0.0f;
#pragma unroll
    for (int mt = 0; mt < 2; ++mt)
#pragma unroll
      for (int r = 0; r < 16; ++r) {
        const int m =
            bm + wm + mt * 32 + (r & 3) + 8 * (r >> 2) + 4 * hi;
        const float v = acc[mt][nt][r] * scl + bv;
        if (OUT_F32)
          ((float*)outraw)[(size_t)m * 1024 + n] = v;
        else
          ((unsigned short*)outraw)[(size_t)z * 4096 * 1024 +
                                    (size_t)m * 1024 + n] = f2bf(v);
      }
  }
}

// ---------------------------------------------------------------------------
// Flash attention, q-tile 64, in-block kv-split, no-max exp2 softmax
// (Q pre-scaled by 0.125*log2e).  [r7/r9-verified ~50 us — FROZEN]
//
// Block: 256 thr = 4 waves = 2 q-groups (wq) x 2 kv-streams (ws).
//   wave (wq,ws): 32 q rows = qt*64 + wq*32, kv range = ws*1024 .. +1023,
//   iterated in 16 tiles of KVBLK=64.
// MFMA 32x32x16, S^T form (A = K rows, B = Q cols): lane (hi,l32) holds
//   S^T col q=l32, rows kv = 32mb + 4hi + (r&3) + 8(r>>2)  [m74/m101 layout].
// P stays IN REGISTERS: cvt_pk pairs -> u[mb][g][p] (kv = 32mb+4hi+8g+2p+{0,1});
//   2x v_permlane32_swap_b32 per k-chunk assembles the PV A-frag
//   (lane needs P[q][16ks+8hi+j]) -- no P LDS round-trip, no P barrier.
// LDS: per stream K tile [64 kv][64 d] + V^T tile [64 d][64 kv], 64-short rows
//   with slot^(row&7) XOR swizzle; staged by global_load_lds w=16 with the
//   inverse swizzle pre-applied to the per-lane GLOBAL source address
//   (LDS dest stays linear). Conflict-free ds_read_b128 frag reads.
// Epilogue: streams combine unnormalized O (fp32) + l through LDS (exp2
//   softmax has no running max -> partials are additive), normalize, store.
// LDS 33280 B, VGPR <=128 (launch_bounds 256,4) -> 4 blocks/CU = 16 waves/CU.
// grid (32 qt, 32 bh) = 1024 blocks.
// ---------------------------------------------------------------------------
__global__ __launch_bounds__(256, 4) void attn4(
    const unsigned short* __restrict__ qkv,   // Q plane at 0, K plane at PL
    const unsigned short* __restrict__ vt_g,  // [32][64][2048] (plane 2)
    unsigned short* __restrict__ ab) {
  constexpr size_t PL = (size_t)4096 * 1024;
  const int qt = blockIdx.x, bh = blockIdx.y;
  const int b = bh >> 4, h = bh & 15;

  __shared__ __align__(16) unsigned short kvs[2][2][64 * 64];  // [ws][K,V][.]
  __shared__ float sm_l[2][2][32];                             // [ws][wq][q]

  const int tid = threadIdx.x;
  const int wave = tid >> 6, lane = tid & 63;
  const int ws = wave >> 1, wq = wave & 1;
  const int hi = lane >> 5, l32 = lane & 31;
  const int row8 = lane >> 3;                  // 0..7 (staging row in chunk)
  const int sl = (lane & 7) ^ (row8 & 7);      // pre-swizzled source slot
  const int swz = (l32 & 7) * 8;               // read-side XOR (shorts)

  // Q fragments (B operand): lane holds Q[q=l32][d = kc*16 + hi*8 + j]
  const unsigned short* qrow =
      qkv + (size_t)(b * 2048 + qt * 64 + wq * 32 + l32) * 1024 + h * 64 +
      hi * 8;
  bf16x8 qf[4];
#pragma unroll
  for (int kc = 0; kc < 4; ++kc) qf[kc] = ld_frag(qrow + kc * 16);

  // staging pointers: per-lane global (swizzled), wave-uniform LDS base.
  // wave wq stages chunks wq*4..wq*4+3 (1 KiB each) of its stream's K and V.
  const unsigned short* gK =
      qkv + PL + (size_t)(b * 2048 + ws * 1024 + wq * 32 + row8) * 1024 +
      h * 64 + sl * 8;
  const unsigned short* gV =
      vt_g + (size_t)bh * 64 * 2048 + (size_t)(wq * 32 + row8) * 2048 +
      ws * 1024 + sl * 8;
  unsigned short* lK = &kvs[ws][0][wq * 4 * 512];
  unsigned short* lV = &kvs[ws][1][wq * 4 * 512];

  f32x16 o_acc[2] = {};
  float l_part = 0.0f;

  for (int t = 0; t < 16; ++t) {
    // ---- stage K,V tiles (64 kv) for this stream ----
#pragma unroll
    for (int c = 0; c < 4; ++c) {
      async16(gK + (size_t)c * 8 * 1024, lK + c * 512);
      async16(gV + (size_t)c * 8 * 2048, lV + c * 512);
    }
    gK += 64 * 1024;  // next 64 kv rows
    gV += 64;         // next 64 kv cols
    __syncthreads();

    // ---- QK^T: S^T[kv][q], 2 mb x 4 kc ----
    f32x16 st[2] = {};
#pragma unroll
    for (int mb = 0; mb < 2; ++mb)
#pragma unroll
      for (int kc = 0; kc < 4; ++kc) {
        bf16x8 ak = ld_frag(
            &kvs[ws][0][(mb * 32 + l32) * 64 + (((2 * kc + hi) * 8) ^ swz)]);
        st[mb] = __builtin_amdgcn_mfma_f32_32x32x16_bf16(ak, qf[kc], st[mb],
                                                         0, 0, 0);
      }

    // ---- softmax (no-max exp2) + pack P to bf16 pairs in registers ----
    unsigned int u[2][4][2];
#pragma unroll
    for (int mb = 0; mb < 2; ++mb) {
#pragma unroll
      for (int r = 0; r < 16; ++r) {
        const float p = __builtin_amdgcn_exp2f(st[mb][r]);
        st[mb][r] = p;
        l_part += p;
      }
#pragma unroll
      for (int g = 0; g < 4; ++g) {
        u[mb][g][0] = cvtpk(st[mb][g * 4 + 0], st[mb][g * 4 + 1]);
        u[mb][g][1] = cvtpk(st[mb][g * 4 + 2], st[mb][g * 4 + 3]);
      }
    }

    // ---- PV: O += P.V, A-frags assembled via permlane32_swap ----
#pragma unroll
    for (int ks = 0; ks < 4; ++ks) {
      const int m = ks >> 1, g = (ks & 1) * 2;
      unsigned int a0 = u[m][g][0], b0 = u[m][g + 1][0];
      unsigned int a1 = u[m][g][1], b1 = u[m][g + 1][1];
      // after swap: a' = [a.lo | b.lo], b' = [a.hi | b.hi]
      asm("v_permlane32_swap_b32 %0, %1" : "+v"(a0), "+v"(b0));
      asm("v_permlane32_swap_b32 %0, %1" : "+v"(a1), "+v"(b1));
      union { unsigned int w[4]; bf16x8 f; } pa;
      pa.w[0] = a0; pa.w[1] = a1; pa.w[2] = b0; pa.w[3] = b1;
#pragma unroll
      for (int nb = 0; nb < 2; ++nb) {
        bf16x8 bv = ld_frag(
            &kvs[ws][1][(nb * 32 + l32) * 64 + (((2 * ks + hi) * 8) ^ swz)]);
        o_acc[nb] = __builtin_amdgcn_mfma_f32_32x32x16_bf16(pa.f, bv,
                                                            o_acc[nb], 0, 0, 0);
      }
    }
    __syncthreads();  // all frag reads done -> restage safe
  }

  // ---- cross-stream combine: O = (O0+O1) / (l0+l1) ----
  float lsum = l_part + __shfl_xor(l_part, 32);  // full kv-half sum, q=l32

  float* sm_o = (float*)&kvs[0][0][0];  // [2 wq][32 q][64 d] fp32 = 16 KiB
  if (ws == 1) {
#pragma unroll
    for (int nb = 0; nb < 2; ++nb)
#pragma unroll
      for (int r = 0; r < 16; ++r) {
        const int q = (r & 3) + 8 * (r >> 2) + 4 * hi;
        sm_o[wq * 2048 + q * 64 + nb * 32 + l32] = o_acc[nb][r];
      }
  }
  if (lane < 32) sm_l[ws][wq][l32] = lsum;
  __syncthreads();

  if (ws == 0) {
#pragma unroll
    for (int r = 0; r < 16; ++r) {
      const int q = (r & 3) + 8 * (r >> 2) + 4 * hi;
      const float inv = 1.0f / (sm_l[0][wq][q] + sm_l[1][wq][q]);
      const size_t row = (size_t)(b * 2048 + qt * 64 + wq * 32 + q);
#pragma unroll
      for (int nb = 0; nb < 2; ++nb) {
        const float v =
            (o_acc[nb][r] + sm_o[wq * 2048 + q * 64 + nb * 32 + l32]) * inv;
        ab[row * 1024 + h * 64 + nb * 32 + l32] = f2bf(v);
      }
    }
  }
}

// ---------------------------------------------------------------------------
extern "C" void kernel_launch(void* const* d_in, const int* in_sizes, int n_in,
                              void* d_out, int out_size, void* d_ws,
                              size_t ws_size, hipStream_t stream) {
  const float* x  = (const float*)d_in[0];
  const float* wq = (const float*)d_in[1];
  const float* wk = (const float*)d_in[2];
  const float* wv = (const float*)d_in[3];
  const float* wo = (const float*)d_in[4];
  const float* bo = (const float*)d_in[5];

  constexpr size_t PL = (size_t)4096 * 1024;
  unsigned short* qkv = (unsigned short*)d_ws;   // planes 0=Q 1=K 2=V^T
  unsigned short* xb  = qkv + 3 * PL;            // x bf16 (dead after gemm)
  unsigned short* ab  = xb;                      // attn out overlays xb
  unsigned short* wqb = qkv + 4 * PL;
  unsigned short* wkb = wqb + 1024 * 1024;
  unsigned short* wvb = wkb + 1024 * 1024;
  unsigned short* wob = wvb + 1024 * 1024;

  const float QSCALE = 0.18033688011112042f;  // 0.125 * log2(e)

  cvt_all<<<dim3(2048, 5), 256, 0, stream>>>(x, wq, wk, wv, wo,
                                             xb, wqb, wkb, wvb, wob);
  gemm_bt<false><<<dim3(32, 8, 3), 256, 0, stream>>>(
      xb, wqb, wkb, wvb, nullptr, qkv, QSCALE);   // z==2 writes V^T (plane 2)
  attn4<<<dim3(32, 32), 256, 0, stream>>>(qkv, qkv + 2 * PL, ab);
  gemm_bt<true><<<dim3(32, 8, 1), 256, 0, stream>>>(
      ab, wob, wob, wob, bo, d_out, 1.0f);
}

// Round 12
// 182.676 us; speedup vs baseline: 1.0170x; 1.0027x over previous
//
#include <hip/hip_runtime.h>
#include <hip/hip_bf16.h>

// ---------------------------------------------------------------------------
// HessianCompatibleMultiHeadAttention on MI355X (gfx950).
// Inputs fp32, output fp32. Internal bf16 MFMA.
// B=2, S=2048, D=1024, H=16, Dk=64.
//   cvt_all:      x, wq, wk, wv, wo -> bf16 (grid-stride, 2048 blocks; r12:
//                 old (2048,5) grid had 6144 no-op blocks)
//   gemm_bt<128,false>: qkv = x_bf @ W^T (z=0 Q pre-scaled 0.125*log2e),
//                 BM=128 BN=128 BK=64, 16x16x32 MFMA, grid (32,8,3),
//                 XCD-local (x = m-tile fast dim), z==2 (V) epilogue writes
//                 V^T directly (in-LDS transpose). [r7-verified best config;
//                 r9-r11 falsified BN=64, z-fusion, 32x32 MFMA]
//   attn4:        flash attention q-tile 64, kv-split, in-register P
//                 (cvt_pk + permlane32_swap). [~50-51 us — FROZEN: dbuf(r8),
//                 setprio(r6), reg-prefetch(r5) all null/neg]
//   gemm_bt<128,true>: out = ab @ Wo^T + b_o (fp32), grid (32,8,1).
// Workspace planes (8 MB each): 0=Q 1=K 2=V^T 3=x_bf/ab 4..=weights bf16.
// ---------------------------------------------------------------------------

typedef __bf16 bf16x8 __attribute__((ext_vector_type(8)));
typedef float f32x4 __attribute__((ext_vector_type(4)));
typedef float f32x16 __attribute__((ext_vector_type(16)));

__device__ __forceinline__ unsigned short f2bf(float f) {
  union { float f; unsigned int u; } c; c.f = f;
  unsigned int u = c.u;
  return (unsigned short)((u + 0x7FFFu + ((u >> 16) & 1u)) >> 16);
}

// pack two fp32 -> [bf16(a) | bf16(b)<<16] in ONE VALU op (T12 recipe)
__device__ __forceinline__ unsigned int cvtpk(float a, float b) {
  unsigned int r;
  asm("v_cvt_pk_bf16_f32 %0, %1, %2" : "=v"(r) : "v"(a), "v"(b));
  return r;
}

__device__ __forceinline__ bf16x8 ld_frag(const unsigned short* p) {
  union { uint4 u; bf16x8 b; } c;
  c.u = *(const uint4*)p;   // 16B aligned -> ds_read_b128
  return c.b;
}

__device__ __forceinline__ uint4 cvt8(const float* __restrict__ p) {
  float4 a = *(const float4*)p;
  float4 b = *(const float4*)(p + 4);
  union { uint4 u; unsigned short s[8]; } r;
  r.s[0] = f2bf(a.x); r.s[1] = f2bf(a.y); r.s[2] = f2bf(a.z); r.s[3] = f2bf(a.w);
  r.s[4] = f2bf(b.x); r.s[5] = f2bf(b.y); r.s[6] = f2bf(b.z); r.s[7] = f2bf(b.w);
  return r.u;
}

// async global->LDS, 16B per lane (lds dest = wave-uniform base + lane*16)
typedef __attribute__((address_space(1))) const unsigned int as1_u32;
typedef __attribute__((address_space(3))) unsigned int as3_u32;
__device__ __forceinline__ void async16(const unsigned short* g,
                                        unsigned short* l) {
  __builtin_amdgcn_global_load_lds(
      (as1_u32*)(unsigned long long)g,
      (as3_u32*)(unsigned int)(unsigned long long)l, 16, 0, 0);
}

// ---------------------------------------------------------------------------
// fp32 -> bf16 conversion (memory-bound). Grid-stride, 2048 blocks x 256 thr.
// Flattened vec8 index space: plane 0 (x) = 524288 vec8, planes 1-4
// (weights) = 131072 vec8 each; total 1048576 -> 2 iterations/thread.
// ---------------------------------------------------------------------------
__global__ __launch_bounds__(256) void cvt_all(
    const float* __restrict__ s0, const float* __restrict__ s1,
    const float* __restrict__ s2, const float* __restrict__ s3,
    const float* __restrict__ s4,
    unsigned short* __restrict__ d0, unsigned short* __restrict__ d1,
    unsigned short* __restrict__ d2, unsigned short* __restrict__ d3,
    unsigned short* __restrict__ d4) {
  const float* srcs[5] = {s0, s1, s2, s3, s4};
  unsigned short* dsts[5] = {d0, d1, d2, d3, d4};
  for (int v = blockIdx.x * 256 + threadIdx.x; v < 1048576; v += 2048 * 256) {
    int p, off;
    if (v < 524288) {
      p = 0; off = v;
    } else {
      p = 1 + ((v - 524288) >> 17);
      off = (v - 524288) & 131071;
    }
    *(uint4*)(dsts[p] + (size_t)off * 8) = cvt8(srcs[p] + (size_t)off * 8);
  }
}

// ---------------------------------------------------------------------------
// GEMM: C[m][n] = scl * sum_k A[m][k] W[n][k] (+ bias[n]); bf16 in, fp32 acc.
// N=1024, K=1024. BN=128, BK=64 (m97 recipe), single-buffered, 256 thr.
// BM=128: 4 waves 2x2 of 64x64. qkv path grid (32,8,3); out path (32,8,1).
// Grid: x = m-tile (fast dispatch dim) -> all 8 n-blocks sharing an A-panel
// land on ONE XCD (linear%8 = x%8) -> A-panel fetched once into that L2.
// Staging: global_load_lds w=16, 8-row 1KiB chunks; LDS [row][64] with
// slot^(row&7) XOR swizzle pre-applied to the per-lane GLOBAL source
// address (LDS dest linear). Frag reads ds_read_b128, 2-way (free).
// z==2 (V plane, !OUT_F32): epilogue transposes the 128x128 C-tile in LDS
// (8-short granule XOR swizzle) and writes V^T [bh][d][s] into plane 2.
// [r7-verified 179.7 us config — restored verbatim]
// ---------------------------------------------------------------------------
template <int BM, bool OUT_F32>
__global__ __launch_bounds__(256, 3) void gemm_bt(
    const unsigned short* __restrict__ A,
    const unsigned short* __restrict__ w0,
    const unsigned short* __restrict__ w1,
    const unsigned short* __restrict__ w2,
    const float* __restrict__ bias,
    void* __restrict__ outraw, float z0scale) {
  constexpr int NT = (BM == 128) ? 4 : 2;
  constexpr int RA = BM / 4;  // A rows staged per wave
  const int z = blockIdx.z;
  const unsigned short* W = (z == 0) ? w0 : ((z == 1) ? w1 : w2);
  const float scl = (z == 0) ? z0scale : 1.0f;

  __shared__ unsigned short smem[(BM + 128) * 64];
  unsigned short* a_lds = smem;
  unsigned short* b_lds = smem + BM * 64;

  const int tid = threadIdx.x;
  const int wave = tid >> 6, lane = tid & 63;
  const int quad = lane >> 4, l16 = lane & 15;
  const int wm = (BM == 128) ? (wave >> 1) * 64 : 0;
  const int wn = (BM == 128) ? (wave & 1) * 64 : wave * 32;
  const int bm = blockIdx.x * BM, bn = blockIdx.y * 128;

  // staging: 1 KiB chunk = 8 rows x 64 shorts; lane covers (row8, slot)
  const int r8 = lane >> 3;            // row within chunk (0..7)
  const int sl = (lane & 7) ^ r8;      // inverse-swizzled k-chunk (16B units)
  const unsigned short* ga = A + (size_t)(bm + wave * RA + r8) * 1024 + sl * 8;
  const unsigned short* gb = W + (size_t)(bn + wave * 32 + r8) * 1024 + sl * 8;
  unsigned short* la = &a_lds[wave * RA * 64];
  unsigned short* lb = &b_lds[wave * 32 * 64];

  f32x4 acc[4][NT] = {};

  for (int k0 = 0; k0 < 1024; k0 += 64) {
    // ---- stage A (RA rows/wave) and B (32 rows/wave) ----
#pragma unroll
    for (int c = 0; c < RA / 8; ++c)
      async16(ga + (size_t)c * 8 * 1024, la + c * 512);
#pragma unroll
    for (int c = 0; c < 4; ++c)
      async16(gb + (size_t)c * 8 * 1024, lb + c * 512);
    ga += 64; gb += 64;
    __syncthreads();

    // ---- frag reads: chunk (kk*4+quad) ^ (row&7), row-major [row][64] ----
    bf16x8 af[2][4], bfr[2][NT];
#pragma unroll
    for (int kk = 0; kk < 2; ++kk) {
#pragma unroll
      for (int t = 0; t < 4; ++t) {
        const int row = wm + t * 16 + l16;
        af[kk][t] =
            ld_frag(&a_lds[row * 64 + (((kk * 4 + quad) ^ (row & 7)) * 8)]);
      }
#pragma unroll
      for (int t = 0; t < NT; ++t) {
        const int row = wn + t * 16 + l16;
        bfr[kk][t] =
            ld_frag(&b_lds[row * 64 + (((kk * 4 + quad) ^ (row & 7)) * 8)]);
      }
    }
#pragma unroll
    for (int kk = 0; kk < 2; ++kk)
#pragma unroll
      for (int mt = 0; mt < 4; ++mt)
#pragma unroll
        for (int nt = 0; nt < NT; ++nt)
          acc[mt][nt] = __builtin_amdgcn_mfma_f32_16x16x32_bf16(
              af[kk][mt], bfr[kk][nt], acc[mt][nt], 0, 0, 0);
    __syncthreads();
  }

  // ---- z==2 (V): transposed epilogue -> V^T [bh][d][s] into plane 2 ----
  if (!OUT_F32 && BM == 128 && z == 2) {
    unsigned short* tt = smem;  // [128 n][128 m] bf16, 8-short-granule swizzle
#pragma unroll
    for (int nt = 0; nt < NT; ++nt) {
      const int nl = wn + nt * 16 + l16;
#pragma unroll
      for (int mt = 0; mt < 4; ++mt) {
        const int ml = wm + mt * 16 + quad * 4;
        union { uint2 u; unsigned short s[4]; } pk;
#pragma unroll
        for (int r = 0; r < 4; ++r) pk.s[r] = f2bf(acc[mt][nt][r]);
        const int g = (ml >> 3) ^ (nl & 7);
        *(uint2*)&tt[nl * 128 + g * 8 + (ml & 7)] = pk.u;
      }
    }
    __syncthreads();
    const int nl = tid >> 1, sc = (tid & 1) * 64;
    const int bb = bm >> 11, s0 = bm & 2047;
    const int hh = (bn >> 6) + (nl >> 6);
    unsigned short* vtp = (unsigned short*)outraw + (size_t)2 * 4096 * 1024 +
                          ((size_t)(bb * 16 + hh)) * 131072 +
                          (size_t)(nl & 63) * 2048 + s0 + sc;
#pragma unroll
    for (int k = 0; k < 8; ++k) {
      const int g = ((sc + k * 8) >> 3) ^ (nl & 7);
      *(uint4*)&vtp[k * 8] = *(const uint4*)&tt[nl * 128 + g * 8];
    }
    return;
  }

  // Epilogue: C/D layout col = lane&15, row = quad*4 + reg  [m89-verified]
#pragma unroll
  for (int nt = 0; nt < NT; ++nt) {
    const int n = bn + wn + nt * 16 + l16;
    const float bv = bias ? bias[n] : 0.0f;
#pragma unroll
    for (int mt = 0; mt < 4; ++mt)
#pragma unroll
      for (int r = 0; r < 4; ++r) {
        const int m = bm + wm + mt * 16 + quad * 4 + r;
        const float v = acc[mt][nt][r] * scl + bv;
        if (OUT_F32)
          ((float*)outraw)[(size_t)z * 4096 * 1024 + (size_t)m * 1024 + n] = v;
        else
          ((unsigned short*)outraw)[(size_t)z * 4096 * 1024 +
                                    (size_t)m * 1024 + n] = f2bf(v);
      }
  }
}

// ---------------------------------------------------------------------------
// Flash attention, q-tile 64, in-block kv-split, no-max exp2 softmax
// (Q pre-scaled by 0.125*log2e).  [r7-verified ~50-51 us — FROZEN]
//
// Block: 256 thr = 4 waves = 2 q-groups (wq) x 2 kv-streams (ws).
//   wave (wq,ws): 32 q rows = qt*64 + wq*32, kv range = ws*1024 .. +1023,
//   iterated in 16 tiles of KVBLK=64.
// MFMA 32x32x16, S^T form (A = K rows, B = Q cols): lane (hi,l32) holds
//   S^T col q=l32, rows kv = 32mb + 4hi + (r&3) + 8(r>>2)  [m74/m101 layout].
// P stays IN REGISTERS: cvt_pk pairs -> u[mb][g][p] (kv = 32mb+4hi+8g+2p+{0,1});
//   2x v_permlane32_swap_b32 per k-chunk assembles the PV A-frag
//   (lane needs P[q][16ks+8hi+j]) -- no P LDS round-trip, no P barrier.
// LDS: per stream K tile [64 kv][64 d] + V^T tile [64 d][64 kv], 64-short rows
//   with slot^(row&7) XOR swizzle; staged by global_load_lds w=16 with the
//   inverse swizzle pre-applied to the per-lane GLOBAL source address
//   (LDS dest stays linear). Conflict-free ds_read_b128 frag reads.
// Epilogue: streams combine unnormalized O (fp32) + l through LDS (exp2
//   softmax has no running max -> partials are additive), normalize, store.
// LDS 33280 B, VGPR <=128 (launch_bounds 256,4) -> 4 blocks/CU = 16 waves/CU.
// grid (32 qt, 32 bh) = 1024 blocks.
// ---------------------------------------------------------------------------
__global__ __launch_bounds__(256, 4) void attn4(
    const unsigned short* __restrict__ qkv,   // Q plane at 0, K plane at PL
    const unsigned short* __restrict__ vt_g,  // [32][64][2048] (plane 2)
    unsigned short* __restrict__ ab) {
  constexpr size_t PL = (size_t)4096 * 1024;
  const int qt = blockIdx.x, bh = blockIdx.y;
  const int b = bh >> 4, h = bh & 15;

  __shared__ __align__(16) unsigned short kvs[2][2][64 * 64];  // [ws][K,V][.]
  __shared__ float sm_l[2][2][32];                             // [ws][wq][q]

  const int tid = threadIdx.x;
  const int wave = tid >> 6, lane = tid & 63;
  const int ws = wave >> 1, wq = wave & 1;
  const int hi = lane >> 5, l32 = lane & 31;
  const int row8 = lane >> 3;                  // 0..7 (staging row in chunk)
  const int sl = (lane & 7) ^ (row8 & 7);      // pre-swizzled source slot
  const int swz = (l32 & 7) * 8;               // read-side XOR (shorts)

  // Q fragments (B operand): lane holds Q[q=l32][d = kc*16 + hi*8 + j]
  const unsigned short* qrow =
      qkv + (size_t)(b * 2048 + qt * 64 + wq * 32 + l32) * 1024 + h * 64 +
      hi * 8;
  bf16x8 qf[4];
#pragma unroll
  for (int kc = 0; kc < 4; ++kc) qf[kc] = ld_frag(qrow + kc * 16);

  // staging pointers: per-lane global (swizzled), wave-uniform LDS base.
  // wave wq stages chunks wq*4..wq*4+3 (1 KiB each) of its stream's K and V.
  const unsigned short* gK =
      qkv + PL + (size_t)(b * 2048 + ws * 1024 + wq * 32 + row8) * 1024 +
      h * 64 + sl * 8;
  const unsigned short* gV =
      vt_g + (size_t)bh * 64 * 2048 + (size_t)(wq * 32 + row8) * 2048 +
      ws * 1024 + sl * 8;
  unsigned short* lK = &kvs[ws][0][wq * 4 * 512];
  unsigned short* lV = &kvs[ws][1][wq * 4 * 512];

  f32x16 o_acc[2] = {};
  float l_part = 0.0f;

  for (int t = 0; t < 16; ++t) {
    // ---- stage K,V tiles (64 kv) for this stream ----
#pragma unroll
    for (int c = 0; c < 4; ++c) {
      async16(gK + (size_t)c * 8 * 1024, lK + c * 512);
      async16(gV + (size_t)c * 8 * 2048, lV + c * 512);
    }
    gK += 64 * 1024;  // next 64 kv rows
    gV += 64;         // next 64 kv cols
    __syncthreads();

    // ---- QK^T: S^T[kv][q], 2 mb x 4 kc ----
    f32x16 st[2] = {};
#pragma unroll
    for (int mb = 0; mb < 2; ++mb)
#pragma unroll
      for (int kc = 0; kc < 4; ++kc) {
        bf16x8 ak = ld_frag(
            &kvs[ws][0][(mb * 32 + l32) * 64 + (((2 * kc + hi) * 8) ^ swz)]);
        st[mb] = __builtin_amdgcn_mfma_f32_32x32x16_bf16(ak, qf[kc], st[mb],
                                                         0, 0, 0);
      }

    // ---- softmax (no-max exp2) + pack P to bf16 pairs in registers ----
    unsigned int u[2][4][2];
#pragma unroll
    for (int mb = 0; mb < 2; ++mb) {
#pragma unroll
      for (int r = 0; r < 16; ++r) {
        const float p = __builtin_amdgcn_exp2f(st[mb][r]);
        st[mb][r] = p;
        l_part += p;
      }
#pragma unroll
      for (int g = 0; g < 4; ++g) {
        u[mb][g][0] = cvtpk(st[mb][g * 4 + 0], st[mb][g * 4 + 1]);
        u[mb][g][1] = cvtpk(st[mb][g * 4 + 2], st[mb][g * 4 + 3]);
      }
    }

    // ---- PV: O += P.V, A-frags assembled via permlane32_swap ----
#pragma unroll
    for (int ks = 0; ks < 4; ++ks) {
      const int m = ks >> 1, g = (ks & 1) * 2;
      unsigned int a0 = u[m][g][0], b0 = u[m][g + 1][0];
      unsigned int a1 = u[m][g][1], b1 = u[m][g + 1][1];
      // after swap: a' = [a.lo | b.lo], b' = [a.hi | b.hi]
      asm("v_permlane32_swap_b32 %0, %1" : "+v"(a0), "+v"(b0));
      asm("v_permlane32_swap_b32 %0, %1" : "+v"(a1), "+v"(b1));
      union { unsigned int w[4]; bf16x8 f; } pa;
      pa.w[0] = a0; pa.w[1] = a1; pa.w[2] = b0; pa.w[3] = b1;
#pragma unroll
      for (int nb = 0; nb < 2; ++nb) {
        bf16x8 bv = ld_frag(
            &kvs[ws][1][(nb * 32 + l32) * 64 + (((2 * ks + hi) * 8) ^ swz)]);
        o_acc[nb] = __builtin_amdgcn_mfma_f32_32x32x16_bf16(pa.f, bv,
                                                            o_acc[nb], 0, 0, 0);
      }
    }
    __syncthreads();  // all frag reads done -> restage safe
  }

  // ---- cross-stream combine: O = (O0+O1) / (l0+l1) ----
  float lsum = l_part + __shfl_xor(l_part, 32);  // full kv-half sum, q=l32

  float* sm_o = (float*)&kvs[0][0][0];  // [2 wq][32 q][64 d] fp32 = 16 KiB
  if (ws == 1) {
#pragma unroll
    for (int nb = 0; nb < 2; ++nb)
#pragma unroll
      for (int r = 0; r < 16; ++r) {
        const int q = (r & 3) + 8 * (r >> 2) + 4 * hi;
        sm_o[wq * 2048 + q * 64 + nb * 32 + l32] = o_acc[nb][r];
      }
  }
  if (lane < 32) sm_l[ws][wq][l32] = lsum;
  __syncthreads();

  if (ws == 0) {
#pragma unroll
    for (int r = 0; r < 16; ++r) {
      const int q = (r & 3) + 8 * (r >> 2) + 4 * hi;
      const float inv = 1.0f / (sm_l[0][wq][q] + sm_l[1][wq][q]);
      const size_t row = (size_t)(b * 2048 + qt * 64 + wq * 32 + q);
#pragma unroll
      for (int nb = 0; nb < 2; ++nb) {
        const float v =
            (o_acc[nb][r] + sm_o[wq * 2048 + q * 64 + nb * 32 + l32]) * inv;
        ab[row * 1024 + h * 64 + nb * 32 + l32] = f2bf(v);
      }
    }
  }
}

// ---------------------------------------------------------------------------
extern "C" void kernel_launch(void* const* d_in, const int* in_sizes, int n_in,
                              void* d_out, int out_size, void* d_ws,
                              size_t ws_size, hipStream_t stream) {
  const float* x  = (const float*)d_in[0];
  const float* wq = (const float*)d_in[1];
  const float* wk = (const float*)d_in[2];
  const float* wv = (const float*)d_in[3];
  const float* wo = (const float*)d_in[4];
  const float* bo = (const float*)d_in[5];

  constexpr size_t PL = (size_t)4096 * 1024;
  unsigned short* qkv = (unsigned short*)d_ws;   // planes 0=Q 1=K 2=V^T
  unsigned short* xb  = qkv + 3 * PL;            // x bf16 (dead after gemm)
  unsigned short* ab  = xb;                      // attn out overlays xb
  unsigned short* wqb = qkv + 4 * PL;
  unsigned short* wkb = wqb + 1024 * 1024;
  unsigned short* wvb = wkb + 1024 * 1024;
  unsigned short* wob = wvb + 1024 * 1024;

  const float QSCALE = 0.18033688011112042f;  // 0.125 * log2(e)

  cvt_all<<<dim3(2048), 256, 0, stream>>>(x, wq, wk, wv, wo,
                                          xb, wqb, wkb, wvb, wob);
  gemm_bt<128, false><<<dim3(32, 8, 3), 256, 0, stream>>>(
      xb, wqb, wkb, wvb, nullptr, qkv, QSCALE);   // z==2 writes V^T (plane 2)
  attn4<<<dim3(32, 32), 256, 0, stream>>>(qkv, qkv + 2 * PL, ab);
  gemm_bt<128, true><<<dim3(32, 8, 1), 256, 0, stream>>>(
      ab, wob, wob, wob, bo, d_out, 1.0f);
}

// Round 13
// 181.111 us; speedup vs baseline: 1.0258x; 1.0086x over previous
//
#include <hip/hip_runtime.h>
#include <hip/hip_bf16.h>

// ---------------------------------------------------------------------------
// HessianCompatibleMultiHeadAttention on MI355X (gfx950).
// Inputs fp32, output fp32. Internal bf16 MFMA.
// B=2, S=2048, D=1024, H=16, Dk=64.
//   cvt_all:      x, wq, wk, wv, wo  -> bf16  [r7 version]
//   gemm_bt<128,false>: qkv = x_bf @ W^T (z=0 Q pre-scaled 0.125*log2e),
//                 BM=128 BN=128 BK=64, 16x16x32 MFMA, grid (32,8,3),
//                 XCD-local (x = m-tile fast dim), z==2 (V) epilogue writes
//                 V^T directly. [r7-verified best config]
//   attn4:        flash attention q-tile 64, kv-split, in-register P
//                 (cvt_pk + permlane32_swap). r13: bh moved to blockIdx.x
//                 (fast dim) -> XCD = bh%8 -> each XCD owns 4 bh values,
//                 K/V working set 2 MB fits L2 (was 16 MB, thrashing; FETCH
//                 69.7 MB vs ~25 ideal). Compute structure FROZEN since r7.
//   gemm_bt<128,true>: out = ab @ Wo^T + b_o (fp32), grid (32,8,1).
// Workspace planes (8 MB each): 0=Q 1=K 2=V^T 3=x_bf/ab 4..=weights bf16.
// Falsified levers: attn dbuf(r8), setprio(r6), reg-prefetch(r5, scratch
// spill), GEMM dbuf(r3), BN=64(r9), z-fusion(r10), 32x32 GEMM MFMA(r11).
// ---------------------------------------------------------------------------

typedef __bf16 bf16x8 __attribute__((ext_vector_type(8)));
typedef float f32x4 __attribute__((ext_vector_type(4)));
typedef float f32x16 __attribute__((ext_vector_type(16)));

__device__ __forceinline__ unsigned short f2bf(float f) {
  union { float f; unsigned int u; } c; c.f = f;
  unsigned int u = c.u;
  return (unsigned short)((u + 0x7FFFu + ((u >> 16) & 1u)) >> 16);
}

// pack two fp32 -> [bf16(a) | bf16(b)<<16] in ONE VALU op (T12 recipe)
__device__ __forceinline__ unsigned int cvtpk(float a, float b) {
  unsigned int r;
  asm("v_cvt_pk_bf16_f32 %0, %1, %2" : "=v"(r) : "v"(a), "v"(b));
  return r;
}

__device__ __forceinline__ bf16x8 ld_frag(const unsigned short* p) {
  union { uint4 u; bf16x8 b; } c;
  c.u = *(const uint4*)p;   // 16B aligned -> ds_read_b128
  return c.b;
}

__device__ __forceinline__ uint4 cvt8(const float* __restrict__ p) {
  float4 a = *(const float4*)p;
  float4 b = *(const float4*)(p + 4);
  union { uint4 u; unsigned short s[8]; } r;
  r.s[0] = f2bf(a.x); r.s[1] = f2bf(a.y); r.s[2] = f2bf(a.z); r.s[3] = f2bf(a.w);
  r.s[4] = f2bf(b.x); r.s[5] = f2bf(b.y); r.s[6] = f2bf(b.z); r.s[7] = f2bf(b.w);
  return r.u;
}

// async global->LDS, 16B per lane (lds dest = wave-uniform base + lane*16)
typedef __attribute__((address_space(1))) const unsigned int as1_u32;
typedef __attribute__((address_space(3))) unsigned int as3_u32;
__device__ __forceinline__ void async16(const unsigned short* g,
                                        unsigned short* l) {
  __builtin_amdgcn_global_load_lds(
      (as1_u32*)(unsigned long long)g,
      (as3_u32*)(unsigned int)(unsigned long long)l, 16, 0, 0);
}

// ---------------------------------------------------------------------------
// fp32 -> bf16 conversion (memory-bound). grid (2048, 5).  [r7 version]
// ---------------------------------------------------------------------------
__global__ __launch_bounds__(256) void cvt_all(
    const float* __restrict__ s0, const float* __restrict__ s1,
    const float* __restrict__ s2, const float* __restrict__ s3,
    const float* __restrict__ s4,
    unsigned short* __restrict__ d0, unsigned short* __restrict__ d1,
    unsigned short* __restrict__ d2, unsigned short* __restrict__ d3,
    unsigned short* __restrict__ d4) {
  const float* srcs[5] = {s0, s1, s2, s3, s4};
  unsigned short* dsts[5] = {d0, d1, d2, d3, d4};
  const int ns[5] = {4194304, 1048576, 1048576, 1048576, 1048576};
  const int y = blockIdx.y;
  const int idx = (blockIdx.x * 256 + threadIdx.x) * 8;
  if (idx >= ns[y]) return;
  *(uint4*)(dsts[y] + idx) = cvt8(srcs[y] + idx);
}

// ---------------------------------------------------------------------------
// GEMM: C[m][n] = scl * sum_k A[m][k] W[n][k] (+ bias[n]); bf16 in, fp32 acc.
// N=1024, K=1024. BN=128, BK=64 (m97 recipe), single-buffered, 256 thr.
// BM=128: 4 waves 2x2 of 64x64. qkv path grid (32,8,3); out path (32,8,1).
// Grid: x = m-tile (fast dispatch dim) -> all 8 n-blocks sharing an A-panel
// land on ONE XCD (linear%8 = x%8) -> A-panel fetched once into that L2.
// Staging: global_load_lds w=16, 8-row 1KiB chunks; LDS [row][64] with
// slot^(row&7) XOR swizzle pre-applied to the per-lane GLOBAL source
// address (LDS dest linear). Frag reads ds_read_b128, 2-way (free).
// z==2 (V plane, !OUT_F32): epilogue transposes the 128x128 C-tile in LDS
// (8-short granule XOR swizzle) and writes V^T [bh][d][s] into plane 2.
// [r7-verified 179.7 us config — restored verbatim]
// ---------------------------------------------------------------------------
template <int BM, bool OUT_F32>
__global__ __launch_bounds__(256, 3) void gemm_bt(
    const unsigned short* __restrict__ A,
    const unsigned short* __restrict__ w0,
    const unsigned short* __restrict__ w1,
    const unsigned short* __restrict__ w2,
    const float* __restrict__ bias,
    void* __restrict__ outraw, float z0scale) {
  constexpr int NT = (BM == 128) ? 4 : 2;
  constexpr int RA = BM / 4;  // A rows staged per wave
  const int z = blockIdx.z;
  const unsigned short* W = (z == 0) ? w0 : ((z == 1) ? w1 : w2);
  const float scl = (z == 0) ? z0scale : 1.0f;

  __shared__ unsigned short smem[(BM + 128) * 64];
  unsigned short* a_lds = smem;
  unsigned short* b_lds = smem + BM * 64;

  const int tid = threadIdx.x;
  const int wave = tid >> 6, lane = tid & 63;
  const int quad = lane >> 4, l16 = lane & 15;
  const int wm = (BM == 128) ? (wave >> 1) * 64 : 0;
  const int wn = (BM == 128) ? (wave & 1) * 64 : wave * 32;
  const int bm = blockIdx.x * BM, bn = blockIdx.y * 128;

  // staging: 1 KiB chunk = 8 rows x 64 shorts; lane covers (row8, slot)
  const int r8 = lane >> 3;            // row within chunk (0..7)
  const int sl = (lane & 7) ^ r8;      // inverse-swizzled k-chunk (16B units)
  const unsigned short* ga = A + (size_t)(bm + wave * RA + r8) * 1024 + sl * 8;
  const unsigned short* gb = W + (size_t)(bn + wave * 32 + r8) * 1024 + sl * 8;
  unsigned short* la = &a_lds[wave * RA * 64];
  unsigned short* lb = &b_lds[wave * 32 * 64];

  f32x4 acc[4][NT] = {};

  for (int k0 = 0; k0 < 1024; k0 += 64) {
    // ---- stage A (RA rows/wave) and B (32 rows/wave) ----
#pragma unroll
    for (int c = 0; c < RA / 8; ++c)
      async16(ga + (size_t)c * 8 * 1024, la + c * 512);
#pragma unroll
    for (int c = 0; c < 4; ++c)
      async16(gb + (size_t)c * 8 * 1024, lb + c * 512);
    ga += 64; gb += 64;
    __syncthreads();

    // ---- frag reads: chunk (kk*4+quad) ^ (row&7), row-major [row][64] ----
    bf16x8 af[2][4], bfr[2][NT];
#pragma unroll
    for (int kk = 0; kk < 2; ++kk) {
#pragma unroll
      for (int t = 0; t < 4; ++t) {
        const int row = wm + t * 16 + l16;
        af[kk][t] =
            ld_frag(&a_lds[row * 64 + (((kk * 4 + quad) ^ (row & 7)) * 8)]);
      }
#pragma unroll
      for (int t = 0; t < NT; ++t) {
        const int row = wn + t * 16 + l16;
        bfr[kk][t] =
            ld_frag(&b_lds[row * 64 + (((kk * 4 + quad) ^ (row & 7)) * 8)]);
      }
    }
#pragma unroll
    for (int kk = 0; kk < 2; ++kk)
#pragma unroll
      for (int mt = 0; mt < 4; ++mt)
#pragma unroll
        for (int nt = 0; nt < NT; ++nt)
          acc[mt][nt] = __builtin_amdgcn_mfma_f32_16x16x32_bf16(
              af[kk][mt], bfr[kk][nt], acc[mt][nt], 0, 0, 0);
    __syncthreads();
  }

  // ---- z==2 (V): transposed epilogue -> V^T [bh][d][s] into plane 2 ----
  if (!OUT_F32 && BM == 128 && z == 2) {
    unsigned short* tt = smem;  // [128 n][128 m] bf16, 8-short-granule swizzle
#pragma unroll
    for (int nt = 0; nt < NT; ++nt) {
      const int nl = wn + nt * 16 + l16;
#pragma unroll
      for (int mt = 0; mt < 4; ++mt) {
        const int ml = wm + mt * 16 + quad * 4;
        union { uint2 u; unsigned short s[4]; } pk;
#pragma unroll
        for (int r = 0; r < 4; ++r) pk.s[r] = f2bf(acc[mt][nt][r]);
        const int g = (ml >> 3) ^ (nl & 7);
        *(uint2*)&tt[nl * 128 + g * 8 + (ml & 7)] = pk.u;
      }
    }
    __syncthreads();
    const int nl = tid >> 1, sc = (tid & 1) * 64;
    const int bb = bm >> 11, s0 = bm & 2047;
    const int hh = (bn >> 6) + (nl >> 6);
    unsigned short* vtp = (unsigned short*)outraw + (size_t)2 * 4096 * 1024 +
                          ((size_t)(bb * 16 + hh)) * 131072 +
                          (size_t)(nl & 63) * 2048 + s0 + sc;
#pragma unroll
    for (int k = 0; k < 8; ++k) {
      const int g = ((sc + k * 8) >> 3) ^ (nl & 7);
      *(uint4*)&vtp[k * 8] = *(const uint4*)&tt[nl * 128 + g * 8];
    }
    return;
  }

  // Epilogue: C/D layout col = lane&15, row = quad*4 + reg  [m89-verified]
#pragma unroll
  for (int nt = 0; nt < NT; ++nt) {
    const int n = bn + wn + nt * 16 + l16;
    const float bv = bias ? bias[n] : 0.0f;
#pragma unroll
    for (int mt = 0; mt < 4; ++mt)
#pragma unroll
      for (int r = 0; r < 4; ++r) {
        const int m = bm + wm + mt * 16 + quad * 4 + r;
        const float v = acc[mt][nt][r] * scl + bv;
        if (OUT_F32)
          ((float*)outraw)[(size_t)z * 4096 * 1024 + (size_t)m * 1024 + n] = v;
        else
          ((unsigned short*)outraw)[(size_t)z * 4096 * 1024 +
                                    (size_t)m * 1024 + n] = f2bf(v);
      }
  }
}

// ---------------------------------------------------------------------------
// Flash attention, q-tile 64, in-block kv-split, no-max exp2 softmax
// (Q pre-scaled by 0.125*log2e).  [compute structure FROZEN since r7]
//
// r13 grid change: bh = blockIdx.x (FAST dim), qt = blockIdx.y.
//   Dispatch-linear = bh + 32*qt -> XCD = bh % 8 -> each XCD owns the 4 bh
//   values ≡ x (mod 8); its K/V working set = 4 x 512 KB = 2 MB, fits the
//   4 MB per-XCD L2 (old qt-fast mapping gave every XCD all 32 bh = 16 MB,
//   thrashing; FETCH_SIZE 69.7 MB vs ~25 MB ideal). All 128 blocks of an
//   XCD are co-resident in one occupancy pass (4 blocks/CU x 32 CU).
//
// Block: 256 thr = 4 waves = 2 q-groups (wq) x 2 kv-streams (ws).
//   wave (wq,ws): 32 q rows = qt*64 + wq*32, kv range = ws*1024 .. +1023,
//   iterated in 16 tiles of KVBLK=64.
// MFMA 32x32x16, S^T form (A = K rows, B = Q cols): lane (hi,l32) holds
//   S^T col q=l32, rows kv = 32mb + 4hi + (r&3) + 8(r>>2)  [m74/m101 layout].
// P stays IN REGISTERS: cvt_pk pairs -> u[mb][g][p] (kv = 32mb+4hi+8g+2p+{0,1});
//   2x v_permlane32_swap_b32 per k-chunk assembles the PV A-frag
//   (lane needs P[q][16ks+8hi+j]) -- no P LDS round-trip, no P barrier.
// LDS: per stream K tile [64 kv][64 d] + V^T tile [64 d][64 kv], 64-short rows
//   with slot^(row&7) XOR swizzle; staged by global_load_lds w=16 with the
//   inverse swizzle pre-applied to the per-lane GLOBAL source address
//   (LDS dest stays linear). Conflict-free ds_read_b128 frag reads.
// Epilogue: streams combine unnormalized O (fp32) + l through LDS (exp2
//   softmax has no running max -> partials are additive), normalize, store.
// LDS 33280 B, VGPR <=128 (launch_bounds 256,4) -> 4 blocks/CU = 16 waves/CU.
// grid (32 bh, 32 qt) = 1024 blocks.
// ---------------------------------------------------------------------------
__global__ __launch_bounds__(256, 4) void attn4(
    const unsigned short* __restrict__ qkv,   // Q plane at 0, K plane at PL
    const unsigned short* __restrict__ vt_g,  // [32][64][2048] (plane 2)
    unsigned short* __restrict__ ab) {
  constexpr size_t PL = (size_t)4096 * 1024;
  const int bh = blockIdx.x, qt = blockIdx.y;  // r13: bh on the FAST dim
  const int b = bh >> 4, h = bh & 15;

  __shared__ __align__(16) unsigned short kvs[2][2][64 * 64];  // [ws][K,V][.]
  __shared__ float sm_l[2][2][32];                             // [ws][wq][q]

  const int tid = threadIdx.x;
  const int wave = tid >> 6, lane = tid & 63;
  const int ws = wave >> 1, wq = wave & 1;
  const int hi = lane >> 5, l32 = lane & 31;
  const int row8 = lane >> 3;                  // 0..7 (staging row in chunk)
  const int sl = (lane & 7) ^ (row8 & 7);      // pre-swizzled source slot
  const int swz = (l32 & 7) * 8;               // read-side XOR (shorts)

  // Q fragments (B operand): lane holds Q[q=l32][d = kc*16 + hi*8 + j]
  const unsigned short* qrow =
      qkv + (size_t)(b * 2048 + qt * 64 + wq * 32 + l32) * 1024 + h * 64 +
      hi * 8;
  bf16x8 qf[4];
#pragma unroll
  for (int kc = 0; kc < 4; ++kc) qf[kc] = ld_frag(qrow + kc * 16);

  // staging pointers: per-lane global (swizzled), wave-uniform LDS base.
  // wave wq stages chunks wq*4..wq*4+3 (1 KiB each) of its stream's K and V.
  const unsigned short* gK =
      qkv + PL + (size_t)(b * 2048 + ws * 1024 + wq * 32 + row8) * 1024 +
      h * 64 + sl * 8;
  const unsigned short* gV =
      vt_g + (size_t)bh * 64 * 2048 + (size_t)(wq * 32 + row8) * 2048 +
      ws * 1024 + sl * 8;
  unsigned short* lK = &kvs[ws][0][wq * 4 * 512];
  unsigned short* lV = &kvs[ws][1][wq * 4 * 512];

  f32x16 o_acc[2] = {};
  float l_part = 0.0f;

  for (int t = 0; t < 16; ++t) {
    // ---- stage K,V tiles (64 kv) for this stream ----
#pragma unroll
    for (int c = 0; c < 4; ++c) {
      async16(gK + (size_t)c * 8 * 1024, lK + c * 512);
      async16(gV + (size_t)c * 8 * 2048, lV + c * 512);
    }
    gK += 64 * 1024;  // next 64 kv rows
    gV += 64;         // next 64 kv cols
    __syncthreads();

    // ---- QK^T: S^T[kv][q], 2 mb x 4 kc ----
    f32x16 st[2] = {};
#pragma unroll
    for (int mb = 0; mb < 2; ++mb)
#pragma unroll
      for (int kc = 0; kc < 4; ++kc) {
        bf16x8 ak = ld_frag(
            &kvs[ws][0][(mb * 32 + l32) * 64 + (((2 * kc + hi) * 8) ^ swz)]);
        st[mb] = __builtin_amdgcn_mfma_f32_32x32x16_bf16(ak, qf[kc], st[mb],
                                                         0, 0, 0);
      }

    // ---- softmax (no-max exp2) + pack P to bf16 pairs in registers ----
    unsigned int u[2][4][2];
#pragma unroll
    for (int mb = 0; mb < 2; ++mb) {
#pragma unroll
      for (int r = 0; r < 16; ++r) {
        const float p = __builtin_amdgcn_exp2f(st[mb][r]);
        st[mb][r] = p;
        l_part += p;
      }
#pragma unroll
      for (int g = 0; g < 4; ++g) {
        u[mb][g][0] = cvtpk(st[mb][g * 4 + 0], st[mb][g * 4 + 1]);
        u[mb][g][1] = cvtpk(st[mb][g * 4 + 2], st[mb][g * 4 + 3]);
      }
    }

    // ---- PV: O += P.V, A-frags assembled via permlane32_swap ----
#pragma unroll
    for (int ks = 0; ks < 4; ++ks) {
      const int m = ks >> 1, g = (ks & 1) * 2;
      unsigned int a0 = u[m][g][0], b0 = u[m][g + 1][0];
      unsigned int a1 = u[m][g][1], b1 = u[m][g + 1][1];
      // after swap: a' = [a.lo | b.lo], b' = [a.hi | b.hi]
      asm("v_permlane32_swap_b32 %0, %1" : "+v"(a0), "+v"(b0));
      asm("v_permlane32_swap_b32 %0, %1" : "+v"(a1), "+v"(b1));
      union { unsigned int w[4]; bf16x8 f; } pa;
      pa.w[0] = a0; pa.w[1] = a1; pa.w[2] = b0; pa.w[3] = b1;
#pragma unroll
      for (int nb = 0; nb < 2; ++nb) {
        bf16x8 bv = ld_frag(
            &kvs[ws][1][(nb * 32 + l32) * 64 + (((2 * ks + hi) * 8) ^ swz)]);
        o_acc[nb] = __builtin_amdgcn_mfma_f32_32x32x16_bf16(pa.f, bv,
                                                            o_acc[nb], 0, 0, 0);
      }
    }
    __syncthreads();  // all frag reads done -> restage safe
  }

  // ---- cross-stream combine: O = (O0+O1) / (l0+l1) ----
  float lsum = l_part + __shfl_xor(l_part, 32);  // full kv-half sum, q=l32

  float* sm_o = (float*)&kvs[0][0][0];  // [2 wq][32 q][64 d] fp32 = 16 KiB
  if (ws == 1) {
#pragma unroll
    for (int nb = 0; nb < 2; ++nb)
#pragma unroll
      for (int r = 0; r < 16; ++r) {
        const int q = (r & 3) + 8 * (r >> 2) + 4 * hi;
        sm_o[wq * 2048 + q * 64 + nb * 32 + l32] = o_acc[nb][r];
      }
  }
  if (lane < 32) sm_l[ws][wq][l32] = lsum;
  __syncthreads();

  if (ws == 0) {
#pragma unroll
    for (int r = 0; r < 16; ++r) {
      const int q = (r & 3) + 8 * (r >> 2) + 4 * hi;
      const float inv = 1.0f / (sm_l[0][wq][q] + sm_l[1][wq][q]);
      const size_t row = (size_t)(b * 2048 + qt * 64 + wq * 32 + q);
#pragma unroll
      for (int nb = 0; nb < 2; ++nb) {
        const float v =
            (o_acc[nb][r] + sm_o[wq * 2048 + q * 64 + nb * 32 + l32]) * inv;
        ab[row * 1024 + h * 64 + nb * 32 + l32] = f2bf(v);
      }
    }
  }
}

// ---------------------------------------------------------------------------
extern "C" void kernel_launch(void* const* d_in, const int* in_sizes, int n_in,
                              void* d_out, int out_size, void* d_ws,
                              size_t ws_size, hipStream_t stream) {
  const float* x  = (const float*)d_in[0];
  const float* wq = (const float*)d_in[1];
  const float* wk = (const float*)d_in[2];
  const float* wv = (const float*)d_in[3];
  const float* wo = (const float*)d_in[4];
  const float* bo = (const float*)d_in[5];

  constexpr size_t PL = (size_t)4096 * 1024;
  unsigned short* qkv = (unsigned short*)d_ws;   // planes 0=Q 1=K 2=V^T
  unsigned short* xb  = qkv + 3 * PL;            // x bf16 (dead after gemm)
  unsigned short* ab  = xb;                      // attn out overlays xb
  unsigned short* wqb = qkv + 4 * PL;
  unsigned short* wkb = wqb + 1024 * 1024;
  unsigned short* wvb = wkb + 1024 * 1024;
  unsigned short* wob = wvb + 1024 * 1024;

  const float QSCALE = 0.18033688011112042f;  // 0.125 * log2(e)

  cvt_all<<<dim3(2048, 5), 256, 0, stream>>>(x, wq, wk, wv, wo,
                                             xb, wqb, wkb, wvb, wob);
  gemm_bt<128, false><<<dim3(32, 8, 3), 256, 0, stream>>>(
      xb, wqb, wkb, wvb, nullptr, qkv, QSCALE);   // z==2 writes V^T (plane 2)
  attn4<<<dim3(32, 32), 256, 0, stream>>>(qkv, qkv + 2 * PL, ab);
  gemm_bt<128, true><<<dim3(32, 8, 1), 256, 0, stream>>>(
      ab, wob, wob, wob, bo, d_out, 1.0f);
}